// Round 9
// baseline (173364.587 us; speedup 1.0000x reference)
//
#include <hip/hip_runtime.h>
#include <math.h>

#define NNEUR 300          // NN
#define NFEAT 20           // NF
#define NPADN 320          // padded n-dimension (Wt rows)
#define MDIM  336          // m: 300 r + 20 image + 1 hold + 1 const + 14 pad
#define NOUT  50
#define NPMAC 100          // NPM
#define TSTEPS 500
#define BATCH 1024
#define GW    48           // m-columns per window
#define NWIN  7            // windows per step (7*48 = 336)
#define NC4   12           // float4 chunks per window
#define WINB  61440        // bytes per window buffer = 320*48*4

// Transposed augmented weights Wt[n][m] (NPADN x MDIM):
//   n<300: m<300 -> J[n][m]; m in [300,320) -> I[n][m-300];
//          m==320 -> S[n]; m==321 -> Bb[n]; else 0.   n>=300: 0.
__global__ void build_wt_kernel(const float* __restrict__ J,
                                const float* __restrict__ I,
                                const float* __restrict__ S,
                                const float* __restrict__ Bb,
                                float* __restrict__ Wt) {
    int e = blockIdx.x * 256 + threadIdx.x;
    if (e >= NPADN * MDIM) return;
    int n = e / MDIM, m = e % MDIM;
    float v = 0.0f;
    if (n < NNEUR) {
        if (m < NNEUR)                   v = J[n * NNEUR + m];
        else if (m < NNEUR + NFEAT)      v = I[n * NFEAT + (m - NNEUR)];
        else if (m == NNEUR + NFEAT)     v = S[n];
        else if (m == NNEUR + NFEAT + 1) v = Bb[n];
    }
    Wt[e] = v;
}

// n-split persistent RNN with LDS-windowed weight streaming.
// Round 8 failed because an 84-deep register stream got hoisted & spilled
// (163 GB scratch writes). global_load_lds uses NO dest VGPRs -> unspillable.
// Window: 48 m-cols x all 320 n', double-buffered (2 x 61.4 KB). n' layout:
// wave w owns rows n' = 20w..20w+19 (16 primary n = 16w+q, 4 tail n2).
// wbuf[c4][n'] float4 layout: primary reads are 2-way bank aliased (free).
__global__ __launch_bounds__(1024, 4) void rnn_kernel(
    const float* __restrict__ Wt,     // [NPADN][MDIM]
    const float* __restrict__ data,   // [T][21][B]
    const float* __restrict__ x0,     // [NNEUR]
    const float* __restrict__ fcw,    // [NOUT][NPMAC]
    const float* __restrict__ fcb,    // [NOUT]
    float* __restrict__ out)          // [T][B][NOUT]
{
    __shared__ __align__(16) float4 wbuf[2][NC4][NPADN];   // 122,880 B
    __shared__ __align__(16) float raug2[2][4][MDIM];      // 10,752 B dbuf [p][b][m]
    __shared__ float fcwt[NPMAC][NOUT];                    // 20,000 B
    __shared__ float fcbs[NOUT];

    const int tid = threadIdx.x;
    const int wid = tid >> 6;
    const int l   = tid & 63;
    const int b0  = blockIdx.x * 4;

    const int n    = tid >> 2;              // primary output row (0..255)
    const int b    = tid & 3;
    const int j2   = (l >> 4) & 3;
    const int n2   = 256 + 4 * wid + j2;    // tail output row
    const int b2   = (l >> 2) & 3;
    const int mseg = l & 3;                 // tail m-segment
    const int npri = 20 * wid + (l >> 2);   // primary slot in n' layout
    const int ntl  = 20 * wid + 16 + j2;    // tail slot in n' layout

    // ---- init ----
    for (int i = tid; i < 2 * 4 * MDIM; i += 1024) ((float*)raug2)[i] = 0.0f;
    for (int i = tid; i < NPMAC * NOUT; i += 1024) {
        int pp = i / NOUT, o = i - (i / NOUT) * NOUT;
        fcwt[pp][o] = fcw[o * NPMAC + pp];
    }
    if (tid < NOUT) fcbs[tid] = fcb[tid];
    __syncthreads();
    for (int i = tid; i < NNEUR; i += 1024) {
        float rv = fmaxf(tanhf(x0[i]), 0.0f);
        #pragma unroll
        for (int bb = 0; bb < 4; ++bb) raug2[0][bb][i] = rv;
    }
    if (tid < 8) raug2[tid >> 2][tid & 3][NNEUR + NFEAT + 1] = 1.0f;  // const row
    float4 dstage = make_float4(0.f, 0.f, 0.f, 0.f);
    if (tid < NFEAT + 1) {
        float4 d0 = *reinterpret_cast<const float4*>(data + (size_t)tid * BATCH + b0);
        raug2[0][0][NNEUR + tid] = d0.x; raug2[0][1][NNEUR + tid] = d0.y;
        raug2[0][2][NNEUR + tid] = d0.z; raug2[0][3][NNEUR + tid] = d0.w;
        dstage = *reinterpret_cast<const float4*>(
            data + ((size_t)(NFEAT + 1) + tid) * BATCH + b0);
    }

    // ---- staging descriptors: wave w issues calls {w, w+16, w+32, w+48<60} ----
    // Call c covers float4s idx = c*64 + l of the window image [c4][n'];
    // n' -> global row: wq = n'/20, r = n'%20, row = r<16 ? 16wq+r : 256+4wq+r-16.
    int offA, offB, offC, offD;
#define PREP(CALL, OFF) { \
    int idx_ = (CALL) * 64 + l; int c4_ = idx_ / NPADN; int np_ = idx_ - NPADN * c4_; \
    int wq_ = np_ / 20; int r_ = np_ - 20 * wq_; \
    int row_ = (r_ < 16) ? (16 * wq_ + r_) : (256 + 4 * wq_ + (r_ - 16)); \
    OFF = row_ * MDIM + 4 * c4_; }
    PREP(wid,      offA)
    PREP(wid + 16, offB)
    PREP(wid + 32, offC)
    if (wid < 12) { PREP(wid + 48, offD) } else { offD = 0; }

    float xs  = x0[n];
    float xs2 = (n2 < NNEUR) ? x0[n2] : 0.0f;

#define GLL(SRC, DSTOFF) __builtin_amdgcn_global_load_lds( \
        (const __attribute__((address_space(1))) void*)(SRC), \
        (__attribute__((address_space(3))) void*)((char*)(&wbuf[0][0][0]) + (DSTOFF)), \
        16, 0, 0)

#define STAGE(DBUF, W0) { \
    const int dbase_ = (DBUF) * WINB + wid * 1024; \
    GLL(Wt + offA + (W0), dbase_); \
    GLL(Wt + offB + (W0), dbase_ + 16384); \
    GLL(Wt + offC + (W0), dbase_ + 32768); \
    if (wid < 12) GLL(Wt + offD + (W0), dbase_ + 49152); }

    STAGE(0, 0)                    // window 0 of step 0
    __syncthreads();               // drains staging (compiler emits vmcnt(0))

    int cur = 0, p = 0;
    for (int t = 0; t < TSTEPS; ++t) {
        const int q = p ^ 1;
        float acc0 = 0.f, acc1 = 0.f, acc2 = 0.f, acc3 = 0.f;
        float ta0 = 0.f, ta1 = 0.f, ta2 = 0.f, ta3 = 0.f;

        #pragma unroll
        for (int w = 0; w < NWIN; ++w) {
            // stage next window (or next step's window 0) into the other buffer
            if (w < NWIN - 1)            { STAGE(cur ^ 1, GW * (w + 1)) }
            else if (t + 1 < TSTEPS)     { STAGE(cur ^ 1, 0) }

            // commit data[t+1] into raug2[q] + prefetch data[t+2] (early, w==0)
            if (w == 0 && tid < NFEAT + 1 && t + 1 < TSTEPS) {
                raug2[q][0][NNEUR + tid] = dstage.x;
                raug2[q][1][NNEUR + tid] = dstage.y;
                raug2[q][2][NNEUR + tid] = dstage.z;
                raug2[q][3][NNEUR + tid] = dstage.w;
                if (t + 2 < TSTEPS)
                    dstage = *reinterpret_cast<const float4*>(
                        data + ((size_t)(t + 2) * (NFEAT + 1) + tid) * BATCH + b0);
            }

            // ---- compute window w from wbuf[cur] ----
            {
                const float4* wb = &wbuf[cur][0][0];
                const float* rb  = &raug2[p][b][GW * w];
                #pragma unroll
                for (int c4 = 0; c4 < NC4; ++c4) {
                    const float4 wv = wb[c4 * NPADN + npri];
                    const float4 rv = *reinterpret_cast<const float4*>(rb + 4 * c4);
                    acc0 += wv.x * rv.x; acc1 += wv.y * rv.y;
                    acc2 += wv.z * rv.z; acc3 += wv.w * rv.w;
                }
                const float* rb2 = &raug2[p][b2][GW * w];
                #pragma unroll
                for (int c4t = 0; c4t < 3; ++c4t) {
                    const int c4 = 3 * mseg + c4t;
                    const float4 wv = wb[c4 * NPADN + ntl];
                    const float4 rv = *reinterpret_cast<const float4*>(rb2 + 4 * c4);
                    ta0 += wv.x * rv.x; ta1 += wv.y * rv.y;
                    ta2 += wv.z * rv.z; ta3 += wv.w * rv.w;
                }
            }

            // ---- last window: state update, write r into raug2[q] ----
            if (w == NWIN - 1) {
                float tsum = (ta0 + ta1) + (ta2 + ta3);
                tsum += __shfl_xor(tsum, 1);
                tsum += __shfl_xor(tsum, 2);
                float s   = (acc0 + acc1) + (acc2 + acc3);
                float pre = xs + (s - xs) * 0.1f;       // x + tdx/10
                xs = pre;
                raug2[q][b][n] = fmaxf(tanhf(pre), 0.0f);
                if (mseg == 0 && n2 < NNEUR) {
                    float pre2 = xs2 + (tsum - xs2) * 0.1f;
                    xs2 = pre2;
                    raug2[q][b2][n2] = fmaxf(tanhf(pre2), 0.0f);
                }
            }
            __syncthreads();
            cur ^= 1;
        }

        // ---- Phase D: y = r[:, :100] @ fcw.T + fcb (reads raug2[q]) ----
        if (tid < 800) {
            int pair = tid >> 2, seg = tid & 3;
            int bD = pair / NOUT, oD = pair - (pair / NOUT) * NOUT;
            int pb = seg * 25;
            float y = 0.0f;
            #pragma unroll 5
            for (int k = 0; k < 25; ++k)
                y += raug2[q][bD][pb + k] * fcwt[pb + k][oD];
            y += __shfl_down(y, 1, 4);
            y += __shfl_down(y, 2, 4);
            if (seg == 0)
                out[((size_t)t * BATCH + b0 + bD) * NOUT + oD] = y + fcbs[oD];
        }
        // D reads raug2[q]; step t+1 writes raug2[q^1] only, and its w0
        // barrier orders D before any further reuse.
        p = q;
    }
}

extern "C" void kernel_launch(void* const* d_in, const int* in_sizes, int n_in,
                              void* d_out, int out_size, void* d_ws, size_t ws_size,
                              hipStream_t stream) {
    const float* data = (const float*)d_in[0];
    const float* J    = (const float*)d_in[1];
    const float* I    = (const float*)d_in[2];
    const float* S    = (const float*)d_in[3];
    const float* Bb   = (const float*)d_in[4];
    const float* x0   = (const float*)d_in[5];
    const float* fcw  = (const float*)d_in[6];
    const float* fcb  = (const float*)d_in[7];
    float* out = (float*)d_out;
    float* Wt  = (float*)d_ws;   // NPADN*MDIM*4 = 430,080 bytes

    int wtot = NPADN * MDIM;
    build_wt_kernel<<<(wtot + 255) / 256, 256, 0, stream>>>(J, I, S, Bb, Wt);
    rnn_kernel<<<256, 1024, 0, stream>>>(Wt, data, x0, fcw, fcb, out);
}

// Round 10
// 4548.526 us; speedup vs baseline: 38.1145x; 38.1145x over previous
//
#include <hip/hip_runtime.h>
#include <math.h>

#define NNEUR 300          // NN
#define NFEAT 20           // NF
#define NPAD  320          // padded n-dimension (W cols)
#define MDIM  336          // m: 300 r + 20 image + 1 hold + 1 const + 14 pad
#define NOUT  50
#define NPMAC 100          // NPM
#define TSTEPS 500
#define BATCH 1024
#define NWAVE 16
#define MCHUNK 21          // m-rows per wave
#define NBCOL 8            // batch columns per block (128 blocks total)
#define PSTR  328          // padded part row (float4-aligned, 1312 B)

typedef float v2f __attribute__((ext_vector_type(2)));

// Augmented weight matrix W[m][n] (MDIM x NPAD):
//   m<300: W[m][n] = J[n][m]; m in [300,320): I[n][m-300];
//   m==320: S[n]; m==321: Bb[n]; else (and n>=300): 0.
__global__ void build_w_kernel(const float* __restrict__ J,
                               const float* __restrict__ I,
                               const float* __restrict__ S,
                               const float* __restrict__ Bb,
                               float* __restrict__ W) {
    int e = blockIdx.x * 256 + threadIdx.x;
    if (e >= MDIM * NPAD) return;
    int m = e / NPAD, n = e % NPAD;
    float v = 0.0f;
    if (n < NNEUR) {
        if (m < NNEUR)                   v = J[n * NNEUR + m];
        else if (m < NNEUR + NFEAT)      v = I[n * NFEAT + (m - NNEUR)];
        else if (m == NNEUR + NFEAT)     v = S[n];
        else if (m == NNEUR + NFEAT + 1) v = Bb[n];
    }
    W[e] = v;
}

// Wide-batch persistent RNN: 128 blocks x 1024 threads; block owns 8 batch
// cols -> total L2 W-traffic HALVES vs 256-block/4-col (the round-2 limiter).
// Packed float2 accumulators (v_pk_fma_f32) keep FMA issue at the 4-col
// level and the register demand (~60) under the proven 64-VGPR budget.
// W streamed from L2 with plain coalesced loads (round-2 pattern; rounds
// 3-9 proved pinning/LDS-DMA alternatives all fail).
__global__ __launch_bounds__(1024, 4) void rnn_kernel(
    const float* __restrict__ W,      // [MDIM][NPAD]
    const float* __restrict__ data,   // [T][21][B]
    const float* __restrict__ x0,     // [NNEUR]
    const float* __restrict__ fcw,    // [NOUT][NPMAC]
    const float* __restrict__ fcb,    // [NOUT]
    float* __restrict__ out)          // [T][B][NOUT]
{
    __shared__ __align__(16) float part[8][NBCOL][PSTR];   // 84 KB partials
    __shared__ __align__(16) v2f   raugP[4][MDIM];         // 10.5 KB [bpair][m]
    __shared__ __align__(16) float xs[NBCOL][NPAD];        // 10 KB state x
    __shared__ float fcwt[NPMAC][NOUT];                    // 20 KB [p][o]
    __shared__ float fcbs[NOUT];

    const int tid = threadIdx.x;
    const int wid = tid >> 6;
    const int l   = tid & 63;
    const int b0  = blockIdx.x * NBCOL;
    const int m0  = wid * MCHUNK;

    // ---- init ----
    for (int i = tid; i < 4 * MDIM; i += 1024) ((v2f*)raugP)[i] = (v2f)0.0f;
    for (int i = tid; i < NPMAC * NOUT; i += 1024) {
        int p = i / NOUT, o = i - (i / NOUT) * NOUT;
        fcwt[p][o] = fcw[o * NPMAC + p];
    }
    if (tid < NOUT) fcbs[tid] = fcb[tid];
    __syncthreads();
    for (int i = tid; i < NNEUR; i += 1024) {
        float xv = x0[i];
        float rv = fmaxf(tanhf(xv), 0.0f);
        #pragma unroll
        for (int b = 0; b < NBCOL; ++b) xs[b][i] = xv;
        v2f rr; rr.x = rv; rr.y = rv;
        #pragma unroll
        for (int bp = 0; bp < 4; ++bp) raugP[bp][i] = rr;
    }
    if (tid < 168) {   // data[t=0] rows 300..320
        int f = tid >> 3, bc = tid & 7;
        float d0 = data[(size_t)f * BATCH + b0 + bc];
        reinterpret_cast<float*>(&raugP[bc >> 1][NNEUR + f])[bc & 1] = d0;
    }
    if (tid < 8)       // const row 321 (never changes)
        reinterpret_cast<float*>(&raugP[tid >> 1][NNEUR + NFEAT + 1])[tid & 1] = 1.0f;
    __syncthreads();

    const int df = tid >> 3, dbc = tid & 7;   // data prefetch mapping
    float dpre = 0.0f;

    for (int t = 0; t < TSTEPS; ++t) {
        // prefetch data[t+1] into a register (hidden under Phase B)
        if (tid < 168 && t + 1 < TSTEPS)
            dpre = data[((size_t)(t + 1) * (NFEAT + 1) + df) * BATCH + b0 + dbc];

        // ---- Phase B: per-wave matvec, packed accumulators ----
        v2f acc01[NBCOL], acc23[NBCOL], accT[4];
        #pragma unroll
        for (int b = 0; b < NBCOL; ++b) { acc01[b] = (v2f)0.0f; acc23[b] = (v2f)0.0f; }
        #pragma unroll
        for (int bp = 0; bp < 4; ++bp) accT[bp] = (v2f)0.0f;

        const float* Wp = W + (size_t)m0 * NPAD;
        #pragma unroll 7
        for (int i = 0; i < MCHUNK; ++i) {
            const float4 w4 = *reinterpret_cast<const float4*>(Wp + (size_t)i * NPAD + 4 * l);
            const float  wt = Wp[(size_t)i * NPAD + 256 + l];
            v2f w01; w01.x = w4.x; w01.y = w4.y;
            v2f w23; w23.x = w4.z; w23.y = w4.w;
            v2f wtt; wtt.x = wt;   wtt.y = wt;
            const int row = m0 + i;
            #pragma unroll
            for (int bp = 0; bp < 4; ++bp) {
                const v2f rp = raugP[bp][row];          // ds_read_b64 broadcast
                v2f rs0; rs0.x = rp.x; rs0.y = rp.x;
                v2f rs1; rs1.x = rp.y; rs1.y = rp.y;
                acc01[2 * bp]     += w01 * rs0;
                acc23[2 * bp]     += w23 * rs0;
                acc01[2 * bp + 1] += w01 * rs1;
                acc23[2 * bp + 1] += w23 * rs1;
                accT[bp]          += wtt * rp;
            }
        }

        // ---- two-stage reduce: waves 0-7 write, 8-15 RMW ----
        if (wid < 8) {
            #pragma unroll
            for (int b = 0; b < NBCOL; ++b) {
                float4 v; v.x = acc01[b].x; v.y = acc01[b].y;
                          v.z = acc23[b].x; v.w = acc23[b].y;
                *reinterpret_cast<float4*>(&part[wid][b][4 * l]) = v;
            }
            #pragma unroll
            for (int bp = 0; bp < 4; ++bp) {
                part[wid][2 * bp][256 + l]     = accT[bp].x;
                part[wid][2 * bp + 1][256 + l] = accT[bp].y;
            }
        }
        __syncthreads();
        if (wid >= 8) {
            const int w8 = wid - 8;
            #pragma unroll
            for (int b = 0; b < NBCOL; ++b) {
                float4 p4 = *reinterpret_cast<float4*>(&part[w8][b][4 * l]);
                p4.x += acc01[b].x; p4.y += acc01[b].y;
                p4.z += acc23[b].x; p4.w += acc23[b].y;
                *reinterpret_cast<float4*>(&part[w8][b][4 * l]) = p4;
            }
            #pragma unroll
            for (int bp = 0; bp < 4; ++bp) {
                part[w8][2 * bp][256 + l]     += accT[bp].x;
                part[w8][2 * bp + 1][256 + l] += accT[bp].y;
            }
        }
        __syncthreads();

        // ---- Phase C: reduce 8 partials, state update, write r; commit data ----
        #pragma unroll
        for (int pass = 0; pass < 3; ++pass) {
            int item = tid + pass * 1024;
            if (item < NBCOL * NPAD) {
                int b = item / NPAD, n = item - NPAD * b;
                if (n < NNEUR) {
                    float s = part[0][b][n] + part[1][b][n] + part[2][b][n] + part[3][b][n]
                            + part[4][b][n] + part[5][b][n] + part[6][b][n] + part[7][b][n];
                    float xo  = xs[b][n];
                    float pre = xo + (s - xo) * 0.1f;     // x + tdx/10
                    xs[b][n] = pre;
                    reinterpret_cast<float*>(&raugP[b >> 1][n])[b & 1] =
                        fmaxf(tanhf(pre), 0.0f);
                }
            }
        }
        if (tid < 168 && t + 1 < TSTEPS)
            reinterpret_cast<float*>(&raugP[dbc >> 1][NNEUR + df])[dbc & 1] = dpre;
        __syncthreads();

        // ---- Phase D: y = r[:, :100] @ fcw.T + fcb, 2 threads per (b,o) ----
        if (tid < 800) {
            int pair = tid >> 1, seg = tid & 1;
            int bD = pair / NOUT, oD = pair - (pair / NOUT) * NOUT;
            int pb = seg * 50;
            float y = 0.0f;
            #pragma unroll 10
            for (int k = 0; k < 50; ++k) {
                float rr = reinterpret_cast<const float*>(&raugP[bD >> 1][pb + k])[bD & 1];
                y += rr * fcwt[pb + k][oD];
            }
            y += __shfl_down(y, 1, 2);
            if (seg == 0)
                out[((size_t)t * BATCH + b0 + bD) * NOUT + oD] = y + fcbs[oD];
        }
        // D reads raugP rows <100 between bar3 and next bar1; the next raugP
        // writes (Phase C) happen after next bar2 -> safe, 3 barriers/step.
    }
}

extern "C" void kernel_launch(void* const* d_in, const int* in_sizes, int n_in,
                              void* d_out, int out_size, void* d_ws, size_t ws_size,
                              hipStream_t stream) {
    const float* data = (const float*)d_in[0];
    const float* J    = (const float*)d_in[1];
    const float* I    = (const float*)d_in[2];
    const float* S    = (const float*)d_in[3];
    const float* Bb   = (const float*)d_in[4];
    const float* x0   = (const float*)d_in[5];
    const float* fcw  = (const float*)d_in[6];
    const float* fcb  = (const float*)d_in[7];
    float* out = (float*)d_out;
    float* W   = (float*)d_ws;   // MDIM*NPAD*4 = 430,080 bytes

    int wtot = MDIM * NPAD;
    build_w_kernel<<<(wtot + 255) / 256, 256, 0, stream>>>(J, I, S, Bb, W);
    rnn_kernel<<<BATCH / NBCOL, 1024, 0, stream>>>(W, data, x0, fcw, fcb, out);
}